// Round 6
// baseline (1173.088 us; speedup 1.0000x reference)
//
#include <hip/hip_runtime.h>
#include <hip/hip_bf16.h>

// Problem constants
#define BATCH 128
#define CH    2
#define NN    256
#define DD    256
#define KTOT  131072          // CH*NN*DD
#define KHALF 128             // NN/2

#define KSPLIT 256            // K-slices
#define KLEN   (KTOT / KSPLIT) // 512 k per slice
#define KS     32              // k per stage (one MFMA K)
#define NST    (KLEN / KS)     // 16 stages
#define NTB    128             // cols per block (N half)
#define PITCH  40              // shorts per LDS row (80B: 16B-aligned, bank-stride 20)

typedef short bf16x8 __attribute__((ext_vector_type(8)));
typedef float f32x4  __attribute__((ext_vector_type(4)));

// 2 floats -> packed bf16 hi pair + packed bf16 lo pair (RNE, cvt_pk path)
__device__ __forceinline__ void hilo2(float a, float b, unsigned& hp, unsigned& lp) {
    union { __hip_bfloat162 v; unsigned u; } H, L;
    H.v = __float22bfloat162_rn(float2{a, b});
    hp = H.u;
    float2 hf = __bfloat1622float2(H.v);
    L.v = __float22bfloat162_rn(float2{a - hf.x, b - hf.y});
    lp = L.u;
}

// ---------------------------------------------------------------------------
// Split-K MFMA GEMM, fp32 emulated via bf16 hi/lo 3-pass (hh + hl + lh).
// Block = 256 threads (4 waves as 2M x 2N, wave tile 64x64), tile M=128 N=128.
// Rolled stage loop (small I$); register prefetch distance = 2 stages.
// ---------------------------------------------------------------------------
template <bool ATOMIC>
__global__ __launch_bounds__(256, 3) void gemm_mfma(const float* __restrict__ x,
                                                    const float* __restrict__ W,
                                                    float* __restrict__ zout) {
    __shared__ unsigned short Ah[128][PITCH], Al[128][PITCH];
    __shared__ unsigned short Bh[NTB][PITCH], Bl[NTB][PITCH];

    // XCD-aware decode: the nh-pair of a slice lands on one XCD (x L2 reuse)
    const int bid     = blockIdx.x;
    const int logical = (bid & 7) * 64 + (bid >> 3);
    const int s       = logical >> 1;
    const int nh      = logical & 1;

    const int t  = threadIdx.x;
    const int k0 = s * KLEN;
    const int c  = k0 >> 16;           // channel plane (slice never crosses)
    const int nd_base = k0 & 65535;

    // staging maps: thread owns one A row-halfk and one B col-halfk
    const int ra = t & 127;            // A: batch row
    const int ha = t >> 7;             // A: k-half (16 floats)
    const int cb = t & 127;            // B: local col
    const int hb = t >> 7;             // B: k-half

    const float* xrow = &x[(size_t)ra * KTOT + k0 + 16 * ha];
    const float* wcol = &W[(size_t)(2 * (nd_base + 16 * hb) + c) * NN + nh * NTB + cb];

    auto loadr = [&](float (&av)[16], float (&bv)[16], int st) {
        const float* xp = xrow + st * KS;
        *(float4*)&av[0]  = *(const float4*)&xp[0];
        *(float4*)&av[4]  = *(const float4*)&xp[4];
        *(float4*)&av[8]  = *(const float4*)&xp[8];
        *(float4*)&av[12] = *(const float4*)&xp[12];
        const float* wp = wcol + (size_t)st * KS * 2 * NN;
#pragma unroll
        for (int i = 0; i < 16; ++i)
            bv[i] = wp[(size_t)i * 2 * NN];   // W row stride 2*NN (channel-interleaved)
    };

    auto writest = [&](const float (&av)[16], const float (&bv)[16]) {
        uint4 H0, H1, L0, L1;
        hilo2(av[0],  av[1],  H0.x, L0.x); hilo2(av[2],  av[3],  H0.y, L0.y);
        hilo2(av[4],  av[5],  H0.z, L0.z); hilo2(av[6],  av[7],  H0.w, L0.w);
        hilo2(av[8],  av[9],  H1.x, L1.x); hilo2(av[10], av[11], H1.y, L1.y);
        hilo2(av[12], av[13], H1.z, L1.z); hilo2(av[14], av[15], H1.w, L1.w);
        *(uint4*)&Ah[ra][16 * ha]     = H0;
        *(uint4*)&Ah[ra][16 * ha + 8] = H1;
        *(uint4*)&Al[ra][16 * ha]     = L0;
        *(uint4*)&Al[ra][16 * ha + 8] = L1;
        hilo2(bv[0],  bv[1],  H0.x, L0.x); hilo2(bv[2],  bv[3],  H0.y, L0.y);
        hilo2(bv[4],  bv[5],  H0.z, L0.z); hilo2(bv[6],  bv[7],  H0.w, L0.w);
        hilo2(bv[8],  bv[9],  H1.x, L1.x); hilo2(bv[10], bv[11], H1.y, L1.y);
        hilo2(bv[12], bv[13], H1.z, L1.z); hilo2(bv[14], bv[15], H1.w, L1.w);
        *(uint4*)&Bh[cb][16 * hb]     = H0;
        *(uint4*)&Bh[cb][16 * hb + 8] = H1;
        *(uint4*)&Bl[cb][16 * hb]     = L0;
        *(uint4*)&Bl[cb][16 * hb + 8] = L1;
    };

    // compute maps
    const int lane = t & 63;
    const int wid  = t >> 6;
    const int wm   = (wid >> 1) * 64;
    const int wn   = (wid & 1) * 64;
    const int lr   = lane & 15;
    const int kq   = (lane >> 4) * 8;  // 8-k segment of the frag

    f32x4 acc[4][4] = {};

    auto compute = [&]() {
        bf16x8 a_h[4], a_l[4];
#pragma unroll
        for (int mt = 0; mt < 4; ++mt) {
            a_h[mt] = *(const bf16x8*)&Ah[wm + mt * 16 + lr][kq];
            a_l[mt] = *(const bf16x8*)&Al[wm + mt * 16 + lr][kq];
        }
#pragma unroll
        for (int nt = 0; nt < 4; ++nt) {
            bf16x8 b_h = *(const bf16x8*)&Bh[wn + nt * 16 + lr][kq];
            bf16x8 b_l = *(const bf16x8*)&Bl[wn + nt * 16 + lr][kq];
#pragma unroll
            for (int mt = 0; mt < 4; ++mt) {
                acc[mt][nt] = __builtin_amdgcn_mfma_f32_16x16x32_bf16(a_h[mt], b_h, acc[mt][nt], 0, 0, 0);
                acc[mt][nt] = __builtin_amdgcn_mfma_f32_16x16x32_bf16(a_h[mt], b_l, acc[mt][nt], 0, 0, 0);
                acc[mt][nt] = __builtin_amdgcn_mfma_f32_16x16x32_bf16(a_l[mt], b_h, acc[mt][nt], 0, 0, 0);
            }
        }
    };

    float avA[16], bvA[16], avB[16], bvB[16];
    loadr(avA, bvA, 0);
    loadr(avB, bvB, 1);          // 2 stages in flight before first use
#pragma unroll 1
    for (int st = 0; st < NST; st += 2) {
        __syncthreads();                         // prev compute done
        writest(avA, bvA);
        if (st + 2 < NST) loadr(avA, bvA, st + 2);  // prefetch distance 2
        __syncthreads();                         // stage visible
        compute();
        __syncthreads();
        writest(avB, bvB);
        if (st + 3 < NST) loadr(avB, bvB, st + 3);
        __syncthreads();
        compute();
    }

    // epilogue: C layout col=lane&15, row=(lane>>4)*4+reg  [verified round 2]
#pragma unroll
    for (int mt = 0; mt < 4; ++mt)
#pragma unroll
        for (int nt = 0; nt < 4; ++nt)
#pragma unroll
            for (int r = 0; r < 4; ++r) {
                const int row = wm + mt * 16 + (lane >> 4) * 4 + r;
                const int col = nh * NTB + wn + nt * 16 + lr;
                if (ATOMIC) atomicAdd(&zout[row * NN + col], acc[mt][nt][r]);
                else zout[(size_t)s * (BATCH * NN) + row * NN + col] = acc[mt][nt][r];
            }
}

// ---------------------------------------------------------------------------
// Fused tail: per (batch row, channel) block of 1024 threads:
//   phase 1: parallel reduce of nslices partials -> z[256] in LDS
//   phase 2: rank vs median midpoint, stable compaction -> idx lists in LDS
//   phase 3: gather out[b,c,k,:] = x[b,c,att[k],:] + 1e-4 * x[b,c,drp[k],:]
// Grid = 256 (b = bid>>1, c = bid&1). No global idx round-trip.
// ---------------------------------------------------------------------------
__global__ __launch_bounds__(1024) void select_gather(const float* __restrict__ part,
                                                      int nslices,
                                                      const float* __restrict__ x,
                                                      float* __restrict__ out) {
    __shared__ float zp[4][NN];
    __shared__ float zs[NN];
    __shared__ int   flags[NN];
    __shared__ int   att_l[KHALF], drp_l[KHALF];

    const int b = blockIdx.x >> 1;
    const int cch = blockIdx.x & 1;
    const int t = threadIdx.x;
    const int j = t & 255;
    const int g = t >> 8;

    // phase 1: g-strided slice sum (deterministic per launch config)
    float v = 0.0f;
    for (int s2 = g; s2 < nslices; s2 += 4)
        v += part[(size_t)s2 * (BATCH * NN) + b * NN + j];
    zp[g][j] = v;
    __syncthreads();

    if (t < NN) zs[j] = zp[0][j] + zp[1][j] + zp[2][j] + zp[3][j];
    __syncthreads();

    // phase 2: rank + stable compaction
    if (t < NN) {
        const float z = zs[j];
        int rank = 0;
        for (int i = 0; i < NN; ++i) {
            const float u = zs[i];
            rank += (u < z) || (u == z && i < j);
        }
        flags[j] = (rank >= KHALF) ? 1 : 0;
    }
    __syncthreads();
    if (t < NN) {
        int pos = 0;
        for (int i = 0; i < j; ++i) pos += flags[i];
        if (flags[j]) att_l[pos]     = j;
        else          drp_l[j - pos] = j;
    }
    __syncthreads();

    // phase 3: gather 128 rows of 256 floats (this block's channel)
    const int w    = t >> 6;     // 16 waves
    const int lane = t & 63;
    const float* xc = &x[(size_t)(b * 2 + cch) * NN * DD];
    float* oc = &out[(size_t)(b * 2 + cch) * KHALF * DD];
#pragma unroll
    for (int i = 0; i < 8; ++i) {
        const int k  = w + 16 * i;          // 0..127
        const int ia = att_l[k];
        const int id = drp_l[k];
        const float4 a  = ((const float4*)&xc[(size_t)ia * DD])[lane];
        const float4 d4 = ((const float4*)&xc[(size_t)id * DD])[lane];
        float4 o;
        o.x = a.x + 1e-4f * d4.x;
        o.y = a.y + 1e-4f * d4.y;
        o.z = a.z + 1e-4f * d4.z;
        o.w = a.w + 1e-4f * d4.w;
        ((float4*)&oc[(size_t)k * DD])[lane] = o;
    }
}

extern "C" void kernel_launch(void* const* d_in, const int* in_sizes, int n_in,
                              void* d_out, int out_size, void* d_ws, size_t ws_size,
                              hipStream_t stream) {
    const float* x = (const float*)d_in[0];
    const float* W = (const float*)d_in[1];
    float* out = (float*)d_out;

    const size_t zrow = (size_t)BATCH * NN * sizeof(float);   // 128 KiB
    const size_t pB   = (size_t)KSPLIT * zrow;                // 32 MiB

    if (ws_size >= pB) {
        // deterministic path: per-slice partials + fused tail
        float* part = (float*)d_ws;
        gemm_mfma<false><<<2 * KSPLIT, 256, 0, stream>>>(x, W, part);
        select_gather<<<BATCH * CH, 1024, 0, stream>>>(part, KSPLIT, x, out);
    } else {
        // fallback: atomic accumulation into z (ws too small for partials)
        float* z = (float*)d_ws;
        hipMemsetAsync(z, 0, zrow, stream);
        gemm_mfma<true><<<2 * KSPLIT, 256, 0, stream>>>(x, W, z);
        select_gather<<<BATCH * CH, 1024, 0, stream>>>(z, 1, x, out);
    }
}

// Round 10
// 398.364 us; speedup vs baseline: 2.9448x; 2.9448x over previous
//
#include <hip/hip_runtime.h>
#include <hip/hip_bf16.h>

// Problem constants
#define BATCH 128
#define CH    2
#define NN    256
#define DD    256
#define KTOT  131072          // CH*NN*DD
#define KHALF 128             // NN/2

#define KSPLIT 512            // K-slices (grid 1024 = 4 blocks/CU)
#define KLEN   (KTOT / KSPLIT) // 256 k per slice
#define KS     32              // k per stage (one MFMA K)
#define NST    (KLEN / KS)     // 8 stages
#define NTB    128             // cols per block (N half)
#define PITCH  40              // shorts per LDS row (80B: 16B-aligned, bank-stride 20)

typedef short bf16x8 __attribute__((ext_vector_type(8)));
typedef float f32x4  __attribute__((ext_vector_type(4)));

// 2 floats -> packed bf16 hi pair + packed bf16 lo pair (RNE, cvt_pk path)
__device__ __forceinline__ void hilo2(float a, float b, unsigned& hp, unsigned& lp) {
    union { __hip_bfloat162 v; unsigned u; } H, L;
    H.v = __float22bfloat162_rn(float2{a, b});
    hp = H.u;
    float2 hf = __bfloat1622float2(H.v);
    L.v = __float22bfloat162_rn(float2{a - hf.x, b - hf.y});
    lp = L.u;
}

// ---------------------------------------------------------------------------
// Split-K MFMA GEMM, fp32 emulated via bf16 hi/lo 3-pass (hh + hl + lh).
// Block = 256 threads (4 waves as 2M x 2N, wave tile 64x64), tile M=128 N=128.
// R3-proven stage loop; TLP via 4 blocks/CU hides the barrier-drained loads.
// ---------------------------------------------------------------------------
template <bool ATOMIC>
__global__ __launch_bounds__(256, 4) void gemm_mfma(const float* __restrict__ x,
                                                    const float* __restrict__ W,
                                                    float* __restrict__ zout) {
    __shared__ unsigned short Ah[128][PITCH], Al[128][PITCH];
    __shared__ unsigned short Bh[NTB][PITCH], Bl[NTB][PITCH];

    // XCD-aware decode: the nh-pair of a slice lands on one XCD (x L2 reuse)
    const int bid     = blockIdx.x;
    const int logical = (bid & 7) * 128 + (bid >> 3);
    const int s       = logical >> 1;
    const int nh      = logical & 1;

    const int t  = threadIdx.x;
    const int k0 = s * KLEN;
    const int c  = k0 >> 16;           // channel plane (slice never crosses)
    const int nd_base = k0 & 65535;

    // staging maps: thread owns one A row-halfk and one B col-halfk
    const int ra = t & 127;            // A: batch row
    const int ha = t >> 7;             // A: k-half (16 floats)
    const int cb = t & 127;            // B: local col
    const int hb = t >> 7;             // B: k-half

    const float* xrow = &x[(size_t)ra * KTOT + k0 + 16 * ha];
    const float* wcol = &W[(size_t)(2 * (nd_base + 16 * hb) + c) * NN + nh * NTB + cb];

    float av[16], bv[16];

    auto load_stage = [&](int st) {
        const float* xp = xrow + st * KS;
        *(float4*)&av[0]  = *(const float4*)&xp[0];
        *(float4*)&av[4]  = *(const float4*)&xp[4];
        *(float4*)&av[8]  = *(const float4*)&xp[8];
        *(float4*)&av[12] = *(const float4*)&xp[12];
        const float* wp = wcol + (size_t)st * KS * 2 * NN;
#pragma unroll
        for (int i = 0; i < 16; ++i)
            bv[i] = wp[(size_t)i * 2 * NN];   // W row stride 2*NN (channel-interleaved)
    };

    auto write_stage = [&]() {
        uint4 H0, H1, L0, L1;
        hilo2(av[0],  av[1],  H0.x, L0.x); hilo2(av[2],  av[3],  H0.y, L0.y);
        hilo2(av[4],  av[5],  H0.z, L0.z); hilo2(av[6],  av[7],  H0.w, L0.w);
        hilo2(av[8],  av[9],  H1.x, L1.x); hilo2(av[10], av[11], H1.y, L1.y);
        hilo2(av[12], av[13], H1.z, L1.z); hilo2(av[14], av[15], H1.w, L1.w);
        *(uint4*)&Ah[ra][16 * ha]     = H0;
        *(uint4*)&Ah[ra][16 * ha + 8] = H1;
        *(uint4*)&Al[ra][16 * ha]     = L0;
        *(uint4*)&Al[ra][16 * ha + 8] = L1;
        hilo2(bv[0],  bv[1],  H0.x, L0.x); hilo2(bv[2],  bv[3],  H0.y, L0.y);
        hilo2(bv[4],  bv[5],  H0.z, L0.z); hilo2(bv[6],  bv[7],  H0.w, L0.w);
        hilo2(bv[8],  bv[9],  H1.x, L1.x); hilo2(bv[10], bv[11], H1.y, L1.y);
        hilo2(bv[12], bv[13], H1.z, L1.z); hilo2(bv[14], bv[15], H1.w, L1.w);
        *(uint4*)&Bh[cb][16 * hb]     = H0;
        *(uint4*)&Bh[cb][16 * hb + 8] = H1;
        *(uint4*)&Bl[cb][16 * hb]     = L0;
        *(uint4*)&Bl[cb][16 * hb + 8] = L1;
    };

    // compute maps
    const int lane = t & 63;
    const int wid  = t >> 6;
    const int wm   = (wid >> 1) * 64;
    const int wn   = (wid & 1) * 64;
    const int lr   = lane & 15;
    const int kq   = (lane >> 4) * 8;  // 8-k segment of the frag

    f32x4 acc[4][4] = {};

    auto compute_stage = [&]() {
        bf16x8 a_h[4], a_l[4];
#pragma unroll
        for (int mt = 0; mt < 4; ++mt) {
            a_h[mt] = *(const bf16x8*)&Ah[wm + mt * 16 + lr][kq];
            a_l[mt] = *(const bf16x8*)&Al[wm + mt * 16 + lr][kq];
        }
#pragma unroll
        for (int nt = 0; nt < 4; ++nt) {
            bf16x8 b_h = *(const bf16x8*)&Bh[wn + nt * 16 + lr][kq];
            bf16x8 b_l = *(const bf16x8*)&Bl[wn + nt * 16 + lr][kq];
#pragma unroll
            for (int mt = 0; mt < 4; ++mt) {
                acc[mt][nt] = __builtin_amdgcn_mfma_f32_16x16x32_bf16(a_h[mt], b_h, acc[mt][nt], 0, 0, 0);
                acc[mt][nt] = __builtin_amdgcn_mfma_f32_16x16x32_bf16(a_h[mt], b_l, acc[mt][nt], 0, 0, 0);
                acc[mt][nt] = __builtin_amdgcn_mfma_f32_16x16x32_bf16(a_l[mt], b_h, acc[mt][nt], 0, 0, 0);
            }
        }
    };

    load_stage(0);
    for (int st = 0; st < NST; ++st) {
        __syncthreads();            // previous compute done, LDS reusable
        write_stage();
        __syncthreads();            // stage visible
        if (st + 1 < NST) load_stage(st + 1);  // in flight during compute
        compute_stage();
    }

    // epilogue: C layout col=lane&15, row=(lane>>4)*4+reg  [verified round 2]
#pragma unroll
    for (int mt = 0; mt < 4; ++mt)
#pragma unroll
        for (int nt = 0; nt < 4; ++nt)
#pragma unroll
            for (int r = 0; r < 4; ++r) {
                const int row = wm + mt * 16 + (lane >> 4) * 4 + r;
                const int col = nh * NTB + wn + nt * 16 + lr;
                if (ATOMIC) atomicAdd(&zout[row * NN + col], acc[mt][nt][r]);
                else zout[(size_t)s * (BATCH * NN) + row * NN + col] = acc[mt][nt][r];
            }
}

// ---------------------------------------------------------------------------
// Reduce partials: z[b][j] = sum_s part[s][b][j]. Grid 128 (one per b),
// 256 threads (one per j) -> every load instruction covers 1 KiB contiguous.
// Unroll 8 for ILP (independent loads in flight).
// ---------------------------------------------------------------------------
__global__ __launch_bounds__(256) void reduce1(const float* __restrict__ part,
                                               float* __restrict__ z) {
    const int b = blockIdx.x;
    const int j = threadIdx.x;
    const float* p = &part[b * NN + j];
    float v0 = 0.f, v1 = 0.f, v2 = 0.f, v3 = 0.f;
    float v4 = 0.f, v5 = 0.f, v6 = 0.f, v7 = 0.f;
#pragma unroll 1
    for (int s2 = 0; s2 < KSPLIT; s2 += 8) {
        v0 += p[(size_t)(s2 + 0) * (BATCH * NN)];
        v1 += p[(size_t)(s2 + 1) * (BATCH * NN)];
        v2 += p[(size_t)(s2 + 2) * (BATCH * NN)];
        v3 += p[(size_t)(s2 + 3) * (BATCH * NN)];
        v4 += p[(size_t)(s2 + 4) * (BATCH * NN)];
        v5 += p[(size_t)(s2 + 5) * (BATCH * NN)];
        v6 += p[(size_t)(s2 + 6) * (BATCH * NN)];
        v7 += p[(size_t)(s2 + 7) * (BATCH * NN)];
    }
    z[b * NN + j] = ((v0 + v1) + (v2 + v3)) + ((v4 + v5) + (v6 + v7));
}

// ---------------------------------------------------------------------------
// Fused tail: per (batch row, channel) block of 1024 threads:
//   phase 1: load z[256] into LDS
//   phase 2: rank vs median midpoint, stable compaction -> idx lists in LDS
//   phase 3: gather out[b,c,k,:] = x[b,c,att[k],:] + 1e-4 * x[b,c,drp[k],:]
// ---------------------------------------------------------------------------
__global__ __launch_bounds__(1024) void select_gather(const float* __restrict__ z,
                                                      const float* __restrict__ x,
                                                      float* __restrict__ out) {
    __shared__ float zs[NN];
    __shared__ int   flags[NN];
    __shared__ int   att_l[KHALF], drp_l[KHALF];

    const int b   = blockIdx.x >> 1;
    const int cch = blockIdx.x & 1;
    const int t   = threadIdx.x;
    const int j   = t & 255;

    if (t < NN) zs[j] = z[b * NN + j];
    __syncthreads();

    // phase 2: rank + stable compaction
    if (t < NN) {
        const float v = zs[j];
        int rank = 0;
        for (int i = 0; i < NN; ++i) {
            const float u = zs[i];
            rank += (u < v) || (u == v && i < j);
        }
        flags[j] = (rank >= KHALF) ? 1 : 0;
    }
    __syncthreads();
    if (t < NN) {
        int pos = 0;
        for (int i = 0; i < j; ++i) pos += flags[i];
        if (flags[j]) att_l[pos]     = j;
        else          drp_l[j - pos] = j;
    }
    __syncthreads();

    // phase 3: gather 128 rows of 256 floats (this block's channel)
    const int w    = t >> 6;     // 16 waves
    const int lane = t & 63;
    const float* xc = &x[(size_t)(b * 2 + cch) * NN * DD];
    float* oc = &out[(size_t)(b * 2 + cch) * KHALF * DD];
#pragma unroll
    for (int i = 0; i < 8; ++i) {
        const int k  = w + 16 * i;          // 0..127
        const int ia = att_l[k];
        const int id = drp_l[k];
        const float4 a  = ((const float4*)&xc[(size_t)ia * DD])[lane];
        const float4 d4 = ((const float4*)&xc[(size_t)id * DD])[lane];
        float4 o;
        o.x = a.x + 1e-4f * d4.x;
        o.y = a.y + 1e-4f * d4.y;
        o.z = a.z + 1e-4f * d4.z;
        o.w = a.w + 1e-4f * d4.w;
        ((float4*)&oc[(size_t)k * DD])[lane] = o;
    }
}

extern "C" void kernel_launch(void* const* d_in, const int* in_sizes, int n_in,
                              void* d_out, int out_size, void* d_ws, size_t ws_size,
                              hipStream_t stream) {
    const float* x = (const float*)d_in[0];
    const float* W = (const float*)d_in[1];
    float* out = (float*)d_out;

    const size_t zrow = (size_t)BATCH * NN * sizeof(float);   // 128 KiB
    const size_t pA   = (size_t)KSPLIT * zrow;                // 64 MiB

    if (ws_size >= pA + zrow) {
        // deterministic path: per-slice partials + wide reduce + fused tail
        float* part = (float*)d_ws;
        float* z    = (float*)((char*)d_ws + pA);
        gemm_mfma<false><<<2 * KSPLIT, 256, 0, stream>>>(x, W, part);
        reduce1<<<BATCH, 256, 0, stream>>>(part, z);
        select_gather<<<BATCH * CH, 1024, 0, stream>>>(z, x, out);
    } else {
        // fallback: atomic accumulation into z (ws too small for partials)
        float* z = (float*)d_ws;
        hipMemsetAsync(z, 0, zrow, stream);
        gemm_mfma<true><<<2 * KSPLIT, 256, 0, stream>>>(x, W, z);
        select_gather<<<BATCH * CH, 1024, 0, stream>>>(z, x, out);
    }
}

// Round 12
// 295.442 us; speedup vs baseline: 3.9706x; 1.3484x over previous
//
#include <hip/hip_runtime.h>
#include <hip/hip_bf16.h>

// Problem constants
#define BATCH 128
#define CH    2
#define NN    256
#define DD    256
#define KTOT  131072          // CH*NN*DD
#define KHALF 128             // NN/2

#define KSPLIT 512            // K-slices (grid 1024 = 4 blocks/CU by LDS)
#define KLEN   (KTOT / KSPLIT) // 256 k per slice
#define KS     32              // k per stage (one MFMA K)
#define NST    (KLEN / KS)     // 8 stages
#define NTB    128             // cols per block (N half)
#define PITCH  40              // shorts per LDS row (80B: 16B-aligned, bank-stride 20)
#define RGRP   8               // reduce1 slice groups
#define RSL    (KSPLIT / RGRP) // 64 slices per group

typedef short bf16x8 __attribute__((ext_vector_type(8)));
typedef float f32x4  __attribute__((ext_vector_type(4)));

// 2 floats -> packed bf16 hi pair + packed bf16 lo pair (RNE, cvt_pk path)
__device__ __forceinline__ void hilo2(float a, float b, unsigned& hp, unsigned& lp) {
    union { __hip_bfloat162 v; unsigned u; } H, L;
    H.v = __float22bfloat162_rn(float2{a, b});
    hp = H.u;
    float2 hf = __bfloat1622float2(H.v);
    L.v = __float22bfloat162_rn(float2{a - hf.x, b - hf.y});
    lp = L.u;
}

// ---------------------------------------------------------------------------
// Split-K MFMA GEMM, fp32 emulated via bf16 hi/lo 3-pass (hh + hl + lh).
// Block = 256 threads (4 waves as 2M x 2N, wave tile 64x64), tile M=128 N=128.
// Occupancy comes from LDS (40KB -> 4 blocks/CU) + natural VGPR (84 <= 128
// -> 16 waves/CU). NO aggressive launch-bounds cap: (256,4) squeezed VGPR to
// 64 and spilled ~150MB/launch (R10: WRITE_SIZE 219MB, 175us).
// ---------------------------------------------------------------------------
template <bool ATOMIC>
__global__ __launch_bounds__(256, 2) void gemm_mfma(const float* __restrict__ x,
                                                    const float* __restrict__ W,
                                                    float* __restrict__ zout) {
    __shared__ unsigned short Ah[128][PITCH], Al[128][PITCH];
    __shared__ unsigned short Bh[NTB][PITCH], Bl[NTB][PITCH];

    // XCD-aware decode: the nh-pair of a slice lands on one XCD (x L2 reuse)
    const int bid     = blockIdx.x;
    const int logical = (bid & 7) * 128 + (bid >> 3);
    const int s       = logical >> 1;
    const int nh      = logical & 1;

    const int t  = threadIdx.x;
    const int k0 = s * KLEN;
    const int c  = k0 >> 16;           // channel plane (slice never crosses)
    const int nd_base = k0 & 65535;

    // staging maps: thread owns one A row-halfk and one B col-halfk
    const int ra = t & 127;            // A: batch row
    const int ha = t >> 7;             // A: k-half (16 floats)
    const int cb = t & 127;            // B: local col
    const int hb = t >> 7;             // B: k-half

    const float* xrow = &x[(size_t)ra * KTOT + k0 + 16 * ha];
    const float* wcol = &W[(size_t)(2 * (nd_base + 16 * hb) + c) * NN + nh * NTB + cb];

    float av[16], bv[16];

    auto load_stage = [&](int st) {
        const float* xp = xrow + st * KS;
        *(float4*)&av[0]  = *(const float4*)&xp[0];
        *(float4*)&av[4]  = *(const float4*)&xp[4];
        *(float4*)&av[8]  = *(const float4*)&xp[8];
        *(float4*)&av[12] = *(const float4*)&xp[12];
        const float* wp = wcol + (size_t)st * KS * 2 * NN;
#pragma unroll
        for (int i = 0; i < 16; ++i)
            bv[i] = wp[(size_t)i * 2 * NN];   // W row stride 2*NN (channel-interleaved)
    };

    auto write_stage = [&]() {
        uint4 H0, H1, L0, L1;
        hilo2(av[0],  av[1],  H0.x, L0.x); hilo2(av[2],  av[3],  H0.y, L0.y);
        hilo2(av[4],  av[5],  H0.z, L0.z); hilo2(av[6],  av[7],  H0.w, L0.w);
        hilo2(av[8],  av[9],  H1.x, L1.x); hilo2(av[10], av[11], H1.y, L1.y);
        hilo2(av[12], av[13], H1.z, L1.z); hilo2(av[14], av[15], H1.w, L1.w);
        *(uint4*)&Ah[ra][16 * ha]     = H0;
        *(uint4*)&Ah[ra][16 * ha + 8] = H1;
        *(uint4*)&Al[ra][16 * ha]     = L0;
        *(uint4*)&Al[ra][16 * ha + 8] = L1;
        hilo2(bv[0],  bv[1],  H0.x, L0.x); hilo2(bv[2],  bv[3],  H0.y, L0.y);
        hilo2(bv[4],  bv[5],  H0.z, L0.z); hilo2(bv[6],  bv[7],  H0.w, L0.w);
        hilo2(bv[8],  bv[9],  H1.x, L1.x); hilo2(bv[10], bv[11], H1.y, L1.y);
        hilo2(bv[12], bv[13], H1.z, L1.z); hilo2(bv[14], bv[15], H1.w, L1.w);
        *(uint4*)&Bh[cb][16 * hb]     = H0;
        *(uint4*)&Bh[cb][16 * hb + 8] = H1;
        *(uint4*)&Bl[cb][16 * hb]     = L0;
        *(uint4*)&Bl[cb][16 * hb + 8] = L1;
    };

    // compute maps
    const int lane = t & 63;
    const int wid  = t >> 6;
    const int wm   = (wid >> 1) * 64;
    const int wn   = (wid & 1) * 64;
    const int lr   = lane & 15;
    const int kq   = (lane >> 4) * 8;  // 8-k segment of the frag

    f32x4 acc[4][4] = {};

    auto compute_stage = [&]() {
        bf16x8 a_h[4], a_l[4];
#pragma unroll
        for (int mt = 0; mt < 4; ++mt) {
            a_h[mt] = *(const bf16x8*)&Ah[wm + mt * 16 + lr][kq];
            a_l[mt] = *(const bf16x8*)&Al[wm + mt * 16 + lr][kq];
        }
#pragma unroll
        for (int nt = 0; nt < 4; ++nt) {
            bf16x8 b_h = *(const bf16x8*)&Bh[wn + nt * 16 + lr][kq];
            bf16x8 b_l = *(const bf16x8*)&Bl[wn + nt * 16 + lr][kq];
#pragma unroll
            for (int mt = 0; mt < 4; ++mt) {
                acc[mt][nt] = __builtin_amdgcn_mfma_f32_16x16x32_bf16(a_h[mt], b_h, acc[mt][nt], 0, 0, 0);
                acc[mt][nt] = __builtin_amdgcn_mfma_f32_16x16x32_bf16(a_h[mt], b_l, acc[mt][nt], 0, 0, 0);
                acc[mt][nt] = __builtin_amdgcn_mfma_f32_16x16x32_bf16(a_l[mt], b_h, acc[mt][nt], 0, 0, 0);
            }
        }
    };

    load_stage(0);
    for (int st = 0; st < NST; ++st) {
        __syncthreads();            // previous compute done, LDS reusable
        write_stage();
        __syncthreads();            // stage visible
        if (st + 1 < NST) load_stage(st + 1);  // in flight during compute
        compute_stage();
    }

    // epilogue: C layout col=lane&15, row=(lane>>4)*4+reg  [verified round 2]
#pragma unroll
    for (int mt = 0; mt < 4; ++mt)
#pragma unroll
        for (int nt = 0; nt < 4; ++nt)
#pragma unroll
            for (int r = 0; r < 4; ++r) {
                const int row = wm + mt * 16 + (lane >> 4) * 4 + r;
                const int col = nh * NTB + wn + nt * 16 + lr;
                if (ATOMIC) atomicAdd(&zout[row * NN + col], acc[mt][nt][r]);
                else zout[(size_t)s * (BATCH * NN) + row * NN + col] = acc[mt][nt][r];
            }
}

// ---------------------------------------------------------------------------
// Stage-1 reduce: part2[g][b][j] = sum of 64 slices. Grid 1024 = 8 groups x
// 128 b -> 16 waves/CU in flight (R10's 128-block version was latency-bound
// at ~2 waves/CU). Each load instruction covers 1 KiB contiguous.
// ---------------------------------------------------------------------------
__global__ __launch_bounds__(256) void reduce1(const float* __restrict__ part,
                                               float* __restrict__ part2) {
    const int g = blockIdx.x & (RGRP - 1);
    const int b = blockIdx.x >> 3;
    const int j = threadIdx.x;
    const float* p = &part[(size_t)(g * RSL) * (BATCH * NN) + b * NN + j];
    float v0 = 0.f, v1 = 0.f, v2 = 0.f, v3 = 0.f;
    float v4 = 0.f, v5 = 0.f, v6 = 0.f, v7 = 0.f;
#pragma unroll 1
    for (int s2 = 0; s2 < RSL; s2 += 8) {
        v0 += p[(size_t)(s2 + 0) * (BATCH * NN)];
        v1 += p[(size_t)(s2 + 1) * (BATCH * NN)];
        v2 += p[(size_t)(s2 + 2) * (BATCH * NN)];
        v3 += p[(size_t)(s2 + 3) * (BATCH * NN)];
        v4 += p[(size_t)(s2 + 4) * (BATCH * NN)];
        v5 += p[(size_t)(s2 + 5) * (BATCH * NN)];
        v6 += p[(size_t)(s2 + 6) * (BATCH * NN)];
        v7 += p[(size_t)(s2 + 7) * (BATCH * NN)];
    }
    part2[(size_t)g * (BATCH * NN) + b * NN + j] =
        ((v0 + v1) + (v2 + v3)) + ((v4 + v5) + (v6 + v7));
}

// ---------------------------------------------------------------------------
// Fused tail: per (batch row, channel) block of 1024 threads:
//   phase 1: sum 8 group-partials -> z[256] in LDS
//   phase 2: rank vs median midpoint, stable compaction -> idx lists in LDS
//   phase 3: gather out[b,c,k,:] = x[b,c,att[k],:] + 1e-4 * x[b,c,drp[k],:]
// ---------------------------------------------------------------------------
__global__ __launch_bounds__(1024) void select_gather(const float* __restrict__ part2,
                                                      int ngroups,
                                                      const float* __restrict__ x,
                                                      float* __restrict__ out) {
    __shared__ float zs[NN];
    __shared__ int   flags[NN];
    __shared__ int   att_l[KHALF], drp_l[KHALF];

    const int b   = blockIdx.x >> 1;
    const int cch = blockIdx.x & 1;
    const int t   = threadIdx.x;
    const int j   = t & 255;

    if (t < NN) {
        float v = 0.0f;
        for (int g = 0; g < ngroups; ++g)
            v += part2[(size_t)g * (BATCH * NN) + b * NN + j];
        zs[j] = v;
    }
    __syncthreads();

    // phase 2: rank + stable compaction
    if (t < NN) {
        const float v = zs[j];
        int rank = 0;
        for (int i = 0; i < NN; ++i) {
            const float u = zs[i];
            rank += (u < v) || (u == v && i < j);
        }
        flags[j] = (rank >= KHALF) ? 1 : 0;
    }
    __syncthreads();
    if (t < NN) {
        int pos = 0;
        for (int i = 0; i < j; ++i) pos += flags[i];
        if (flags[j]) att_l[pos]     = j;
        else          drp_l[j - pos] = j;
    }
    __syncthreads();

    // phase 3: gather 128 rows of 256 floats (this block's channel)
    const int w    = t >> 6;     // 16 waves
    const int lane = t & 63;
    const float* xc = &x[(size_t)(b * 2 + cch) * NN * DD];
    float* oc = &out[(size_t)(b * 2 + cch) * KHALF * DD];
#pragma unroll
    for (int i = 0; i < 8; ++i) {
        const int k  = w + 16 * i;          // 0..127
        const int ia = att_l[k];
        const int id = drp_l[k];
        const float4 a  = ((const float4*)&xc[(size_t)ia * DD])[lane];
        const float4 d4 = ((const float4*)&xc[(size_t)id * DD])[lane];
        float4 o;
        o.x = a.x + 1e-4f * d4.x;
        o.y = a.y + 1e-4f * d4.y;
        o.z = a.z + 1e-4f * d4.z;
        o.w = a.w + 1e-4f * d4.w;
        ((float4*)&oc[(size_t)k * DD])[lane] = o;
    }
}

extern "C" void kernel_launch(void* const* d_in, const int* in_sizes, int n_in,
                              void* d_out, int out_size, void* d_ws, size_t ws_size,
                              hipStream_t stream) {
    const float* x = (const float*)d_in[0];
    const float* W = (const float*)d_in[1];
    float* out = (float*)d_out;

    const size_t zrow = (size_t)BATCH * NN * sizeof(float);   // 128 KiB
    const size_t pA   = (size_t)KSPLIT * zrow;                // 64 MiB
    const size_t p2A  = (size_t)RGRP * zrow;                  //  1 MiB

    if (ws_size >= pA + p2A) {
        // deterministic path: per-slice partials + 2-level parallel reduce
        float* part  = (float*)d_ws;
        float* part2 = (float*)((char*)d_ws + pA);
        gemm_mfma<false><<<2 * KSPLIT, 256, 0, stream>>>(x, W, part);
        reduce1<<<RGRP * BATCH, 256, 0, stream>>>(part, part2);
        select_gather<<<BATCH * CH, 1024, 0, stream>>>(part2, RGRP, x, out);
    } else {
        // fallback: atomic accumulation into z (ws too small for partials)
        float* z = (float*)d_ws;
        hipMemsetAsync(z, 0, zrow, stream);
        gemm_mfma<true><<<2 * KSPLIT, 256, 0, stream>>>(x, W, z);
        select_gather<<<BATCH * CH, 1024, 0, stream>>>(z, 1, x, out);
    }
}